// Round 8
// baseline (507.247 us; speedup 1.0000x reference)
//
#include <hip/hip_runtime.h>
#include <cstdint>
#include <cstddef>

#define B_ 2
#define N_ 2048
#define D_ 64
#define E_ 2
#define T_ 5
#define NSPLIT 16

typedef short bf16x8 __attribute__((ext_vector_type(8)));
typedef unsigned short u16x8 __attribute__((ext_vector_type(8)));
typedef float f32x16 __attribute__((ext_vector_type(16)));

__device__ __forceinline__ unsigned short f2bf(float f) {
    unsigned int x = __float_as_uint(f);
    x += 0x7FFFu + ((x >> 16) & 1u);
    return (unsigned short)(x >> 16);
}

// ---------------------------------------------------------------------------
// prep: blocks 0..2047 convert adj -> Abf (bf16 fragment order);
//       blocks 2048..2303 compute transform0 (VT from prop).
// 256 threads. Shared LDS union (~50 KB).
// ---------------------------------------------------------------------------
struct ConvSM { unsigned short sb[32][520]; };
struct TranSM { float hs[64][65]; float Ws[64][64]; float os[64][65]; };

__global__ void prep_kernel(const float* __restrict__ adj, u16x8* __restrict__ Abf,
                            const float* __restrict__ prop,
                            const float* __restrict__ W_in, const float* __restrict__ b_in,
                            const float* __restrict__ W_out, const float* __restrict__ b_out,
                            u16x8* __restrict__ VT) {
    __shared__ union { ConvSM c; TranSM t; } sm;
    int tid = threadIdx.x;

    if (blockIdx.x < 2048) {
        // ------------------ convert ------------------
        int idx = blockIdx.x;
        int rt = idx & 63, c = (idx >> 6) & 7, bd = idx >> 9;
        int b = bd >> 1, dir = bd & 1;
        const float* base = adj + ((size_t)(b * N_ + rt * 32)) * (2 * N_ * E_) + dir * (N_ * E_) + c * 512;

        #pragma unroll
        for (int p = 0; p < 4; ++p) {
            int r = p * 8 + (tid >> 5);
            int i = tid & 31;
            const float* rowp = base + (size_t)r * (2 * N_ * E_);
            #pragma unroll
            for (int j = 0; j < 4; ++j) {
                float4 f = *(const float4*)(rowp + i * 4 + j * 128);
                int kl = i * 4 + j * 128;
                sm.c.sb[r][kl + 0] = f2bf(f.x);
                sm.c.sb[r][kl + 1] = f2bf(f.y);
                sm.c.sb[r][kl + 2] = f2bf(f.z);
                sm.c.sb[r][kl + 3] = f2bf(f.w);
            }
        }
        __syncthreads();

        int l = tid & 63;
        int row = l & 31, khalf = l >> 5;
        int ktl0 = tid >> 6;
        u16x8* dst = Abf + ((size_t)(bd * 64 + rt) * 256 + c * 32 + ktl0) * 64 + l;
        #pragma unroll
        for (int q = 0; q < 8; ++q) {
            int ktl = ktl0 + q * 4;
            u16x8 v = *(const u16x8*)&sm.c.sb[row][ktl * 16 + khalf * 8];
            dst[(size_t)q * 4 * 64] = v;
        }
    } else {
        // ------------------ transform0 ------------------
        int idx = blockIdx.x - 2048;
        int bx = idx & 31, y = idx >> 5;
        int e = y & 1, dir = (y >> 1) & 1, b = y >> 2;
        int bd = y >> 1;
        const float* W = (dir ? W_out : W_in) + e * D_ * D_;
        const float* bias = (dir ? b_out : b_in) + e * D_;
        int n0 = bx * 64;

        #pragma unroll
        for (int i = 0; i < 16; ++i) {
            int ii = tid + 256 * i;
            int r = ii >> 6, c = ii & 63;
            sm.t.hs[r][c] = prop[((size_t)(b * N_ + n0 + r)) * D_ + c];
            sm.t.Ws[r][c] = W[ii];
        }
        __syncthreads();

        int g = tid >> 6, l = tid & 63;
        float acc[16];
        #pragma unroll
        for (int j = 0; j < 16; ++j) acc[j] = bias[g * 16 + j];
        for (int k = 0; k < 64; ++k) {
            float hv = sm.t.hs[l][k];
            #pragma unroll
            for (int j = 0; j < 16; ++j) acc[j] = fmaf(hv, sm.t.Ws[k][g * 16 + j], acc[j]);
        }
        #pragma unroll
        for (int j = 0; j < 16; ++j) sm.t.os[l][g * 16 + j] = acc[j];
        __syncthreads();

        #pragma unroll
        for (int c = 0; c < 2; ++c) {
            int chunk = tid + 256 * c;
            int kt_local = chunk >> 7;
            int sub = (chunk >> 6) & 1;
            int ln = chunk & 63;
            int d = sub * 32 + (ln & 31);
            int nbase = kt_local * 16 + (ln >> 5) * 8;
            u16x8 o;
            #pragma unroll
            for (int j = 0; j < 8; ++j) o[j] = f2bf(sm.t.os[nbase + j][d]);
            int ktg = e * 128 + bx * 4 + kt_local;
            VT[((size_t)bd * 512 + ktg * 2 + sub) * 64 + ln] = o;
        }
    }
}

// ---------------------------------------------------------------------------
// aggregate: apart[split][bd] (2048x64) = A_bf16 @ V_bf16 via MFMA.
// grid (16 rowblocks, 4 bd, 16 splits) = 1024 wgs, 256 thr = 4 waves;
// wave = one 32-row tile, 16 kt per split. High wg count for latency hiding.
// ---------------------------------------------------------------------------
__global__ void __launch_bounds__(256, 4) aggregate_kernel(
        const bf16x8* __restrict__ Abf, const bf16x8* __restrict__ VT,
        float* __restrict__ apart) {
    int bx = blockIdx.x;
    int bd = blockIdx.y;
    int sp = blockIdx.z;
    int tid = threadIdx.x;
    int w = tid >> 6, lane = tid & 63;
    int rt = bx * 4 + w;
    int kt0 = sp * 16;

    const bf16x8* Ap = Abf + ((size_t)(bd * 64 + rt) * 256 + kt0) * 64 + lane;
    const bf16x8* Vp = VT + (size_t)bd * 32768 + (size_t)kt0 * 128 + lane;

    f32x16 acc0 = {}, acc1 = {};
    #pragma unroll 4
    for (int kk = 0; kk < 16; ++kk) {
        bf16x8 a  = Ap[(size_t)kk * 64];
        bf16x8 b0 = Vp[(size_t)kk * 128];
        bf16x8 b1 = Vp[(size_t)kk * 128 + 64];
        acc0 = __builtin_amdgcn_mfma_f32_32x32x16_bf16(a, b0, acc0, 0, 0, 0);
        acc1 = __builtin_amdgcn_mfma_f32_32x32x16_bf16(a, b1, acc1, 0, 0, 0);
    }

    float* Cp = apart + ((size_t)(sp * 4 + bd) * 2048) * 64;
    int col = lane & 31;
    int rbase = rt * 32 + 4 * (lane >> 5);
    #pragma unroll
    for (int reg = 0; reg < 16; ++reg) {
        int row = rbase + (reg & 3) + 8 * (reg >> 2);
        Cp[(size_t)row * 64 + col]      = acc0[reg];
        Cp[(size_t)row * 64 + col + 32] = acc1[reg];
    }
}

// ---------------------------------------------------------------------------
// gru core: one 64-lane unit per node (16 nodes/wg, 1024 thr).
// ---------------------------------------------------------------------------
__device__ __forceinline__ void gru_core(
        const float* __restrict__ h_in, const float* __restrict__ apart,
        const float* __restrict__ Wr, const float* __restrict__ br,
        const float* __restrict__ Wz, const float* __restrict__ bz,
        const float* __restrict__ Wh, const float* __restrict__ bh,
        float sa[16][3][64], float hs[16][64],
        int b, int n0, int g0, int tid)
{
    int nl = tid >> 6, d = tid & 63;
    int n = n0 + nl;
    float ain = 0.f, aout = 0.f;
    #pragma unroll
    for (int sp = 0; sp < NSPLIT; ++sp) {
        ain  += apart[(((size_t)(sp * 4 + b * 2    )) * 2048 + n) * 64 + d];
        aout += apart[(((size_t)(sp * 4 + b * 2 + 1)) * 2048 + n) * 64 + d];
    }
    float h_d = h_in[((size_t)g0 + nl) * 64 + d];
    sa[nl][0][d] = ain;
    sa[nl][1][d] = aout;
    sa[nl][2][d] = h_d;
    float accr = br[d], accz = bz[d];
    #pragma unroll 8
    for (int k = 0; k < 64; ++k) {
        float a0 = sa[nl][0][k], a1 = sa[nl][1][k], a2 = sa[nl][2][k];
        accr = fmaf(a0, Wr[k * 64 + d], accr);
        accr = fmaf(a1, Wr[(64 + k) * 64 + d], accr);
        accr = fmaf(a2, Wr[(128 + k) * 64 + d], accr);
        accz = fmaf(a0, Wz[k * 64 + d], accz);
        accz = fmaf(a1, Wz[(64 + k) * 64 + d], accz);
        accz = fmaf(a2, Wz[(128 + k) * 64 + d], accz);
    }
    float r = 1.0f / (1.0f + expf(-accr));
    float z = 1.0f / (1.0f + expf(-accz));
    sa[nl][2][d] = r * h_d;
    float acch = bh[d];
    #pragma unroll 8
    for (int k = 0; k < 64; ++k) {
        float a0 = sa[nl][0][k], a1 = sa[nl][1][k], a2 = sa[nl][2][k];
        acch = fmaf(a0, Wh[k * 64 + d], acch);
        acch = fmaf(a1, Wh[(64 + k) * 64 + d], acch);
        acch = fmaf(a2, Wh[(128 + k) * 64 + d], acch);
    }
    float hh = tanhf(acch);
    hs[nl][d] = (1.0f - z) * h_d + z * hh;
}

// ---------------------------------------------------------------------------
// gru_mid: gru + h write + VT fragment emit. grid 256 wgs x 1024 thr.
// ---------------------------------------------------------------------------
__global__ void __launch_bounds__(1024, 1) gru_mid_kernel(
        const float* __restrict__ h_in, float* __restrict__ h_out,
        const float* __restrict__ apart,
        const float* __restrict__ Wr, const float* __restrict__ br,
        const float* __restrict__ Wz, const float* __restrict__ bz,
        const float* __restrict__ Wh, const float* __restrict__ bh,
        const float* __restrict__ W_in, const float* __restrict__ b_in,
        const float* __restrict__ W_out, const float* __restrict__ b_out,
        u16x8* __restrict__ VT)
{
    __shared__ float sa[16][3][64];
    __shared__ float hs[16][64];
    __shared__ float os[4][16][66];

    int wg = blockIdx.x, tid = threadIdx.x;
    int g0 = wg * 16;
    int b = g0 >> 11, n0 = g0 & 2047;
    int ktgl = n0 >> 4;

    gru_core(h_in, apart, Wr, br, Wz, bz, Wh, bh, sa, hs, b, n0, g0, tid);

    {
        int nl = tid >> 6, d = tid & 63;
        h_out[((size_t)g0 + nl) * 64 + d] = hs[nl][d];
    }
    __syncthreads();

    int u = tid >> 6, lane = tid & 63;
    {
        int de = u & 3, q = u >> 2;
        int dir = de >> 1, e = de & 1;
        const float* W    = (dir ? W_out : W_in) + e * D_ * D_;
        const float* bias = (dir ? b_out : b_in) + e * D_;
        int d = lane;
        float acc[4];
        #pragma unroll
        for (int i = 0; i < 4; ++i) acc[i] = bias[d];
        for (int k = 0; k < 64; ++k) {
            float wv = W[k * 64 + d];
            #pragma unroll
            for (int i = 0; i < 4; ++i) acc[i] = fmaf(hs[q * 4 + i][k], wv, acc[i]);
        }
        #pragma unroll
        for (int i = 0; i < 4; ++i) os[de][q * 4 + i][d] = acc[i];
    }
    __syncthreads();

    if (u < 8) {
        int de = u >> 1, sub = u & 1;
        int dir = de >> 1, e = de & 1;
        int dd = sub * 32 + (lane & 31);
        int nb = (lane >> 5) * 8;
        u16x8 o;
        #pragma unroll
        for (int j = 0; j < 8; ++j) o[j] = f2bf(os[de][nb + j][dd]);
        int bd = b * 2 + dir;
        int ktg = e * 128 + ktgl;
        VT[((size_t)bd * 512 + ktg * 2 + sub) * 64 + lane] = o;
    }
}

// ---------------------------------------------------------------------------
// gru_last: gru + output head. grid 256 wgs x 1024 thr.
// ---------------------------------------------------------------------------
__global__ void __launch_bounds__(1024, 1) gru_last_kernel(
        const float* __restrict__ h_in,
        const float* __restrict__ apart,
        const float* __restrict__ Wr, const float* __restrict__ br,
        const float* __restrict__ Wz, const float* __restrict__ bz,
        const float* __restrict__ Wh, const float* __restrict__ bh,
        const float* __restrict__ ann,
        const float* __restrict__ Wo1, const float* __restrict__ bo1,
        const float* __restrict__ Wo2, const float* __restrict__ bo2,
        float* __restrict__ out)
{
    __shared__ float sa[16][3][64];
    __shared__ float hs[16][64];
    __shared__ float red[8][2][2];

    int wg = blockIdx.x, tid = threadIdx.x;
    int g0 = wg * 16;
    int b = g0 >> 11, n0 = g0 & 2047;

    gru_core(h_in, apart, Wr, br, Wz, bz, Wh, bh, sa, hs, b, n0, g0, tid);
    __syncthreads();

    int sub = tid >> 7, j = tid & 127;
    int wv = (tid >> 6) & 1;
    #pragma unroll
    for (int s = 0; s < 2; ++s) {
        int nl = sub * 2 + s;
        int g = g0 + nl;
        float acc = bo1[j];
        #pragma unroll
        for (int i = 0; i < 64; ++i) acc = fmaf(hs[nl][i], Wo1[i * 128 + j], acc);
        #pragma unroll
        for (int i = 0; i < 16; ++i) acc = fmaf(ann[(size_t)g * 16 + i], Wo1[(64 + i) * 128 + j], acc);
        float y = 1.0f / (1.0f + expf(-acc));
        float v = y * Wo2[j];
        #pragma unroll
        for (int off = 32; off > 0; off >>= 1) v += __shfl_down(v, off, 64);
        if ((tid & 63) == 0) red[sub][wv][s] = v;
    }
    __syncthreads();
    if (j == 0) {
        #pragma unroll
        for (int s = 0; s < 2; ++s)
            out[g0 + sub * 2 + s] = red[sub][0][s] + red[sub][1][s] + bo2[0];
    }
}

// ---------------------------------------------------------------------------
extern "C" void kernel_launch(void* const* d_in, const int* in_sizes, int n_in,
                              void* d_out, int out_size, void* d_ws, size_t ws_size,
                              hipStream_t stream) {
    const float* prop = (const float*)d_in[0];
    const float* ann  = (const float*)d_in[1];
    const float* adj  = (const float*)d_in[2];
    const float* W_in = (const float*)d_in[3];
    const float* b_in = (const float*)d_in[4];
    const float* W_out= (const float*)d_in[5];
    const float* b_out= (const float*)d_in[6];
    const float* Wr   = (const float*)d_in[7];
    const float* br   = (const float*)d_in[8];
    const float* Wz   = (const float*)d_in[9];
    const float* bz   = (const float*)d_in[10];
    const float* Wh   = (const float*)d_in[11];
    const float* bh   = (const float*)d_in[12];
    const float* Wo1  = (const float*)d_in[13];
    const float* bo1  = (const float*)d_in[14];
    const float* Wo2  = (const float*)d_in[15];
    const float* bo2  = (const float*)d_in[16];
    float* out = (float*)d_out;

    char* ws = (char*)d_ws;
    u16x8* Abf    = (u16x8*)ws;                     // 64 MiB
    u16x8* VT     = (u16x8*)(ws + (64ull << 20));   // 2 MiB
    float* apart  = (float*)(ws + (66ull << 20));   // 34 MiB (16 splits)
    float* h      = (float*)(ws + (100ull << 20));  // 1 MiB

    prep_kernel<<<dim3(2048 + 256), 256, 0, stream>>>(
        adj, Abf, prop, W_in, b_in, W_out, b_out, VT);

    for (int t = 0; t < T_; ++t) {
        aggregate_kernel<<<dim3(16, 4, NSPLIT), 256, 0, stream>>>(
            (const bf16x8*)Abf, (const bf16x8*)VT, apart);
        const float* h_in = (t == 0) ? prop : h;
        if (t < T_ - 1) {
            gru_mid_kernel<<<dim3(256), 1024, 0, stream>>>(
                h_in, h, apart, Wr, br, Wz, bz, Wh, bh,
                W_in, b_in, W_out, b_out, VT);
        } else {
            gru_last_kernel<<<dim3(256), 1024, 0, stream>>>(
                h_in, apart, Wr, br, Wz, bz, Wh, bh,
                ann, Wo1, bo1, Wo2, bo2, out);
        }
    }
}